// Round 9
// baseline (785.975 us; speedup 1.0000x reference)
//
#include <hip/hip_runtime.h>

// SNN model, analyzed:
//  - mem_fict (syn_w matmuls, tau decay) is dead state -> skipped entirely.
//  - mem_phys is uniform across neurons -> 4-bit per-batch states s0,s1.
//  - d0[j,v] = ALPHA*(v-mem_map0[j,v]) * C0[v]  (C = visit counts of state v).
//  - Only real work: XOR-reduce of frames (151.5 MB) per (b,t). HBM/L3-bound.
//  NOTE: cooperative single-kernel fusion regressed 264->492 us (grid capped at
//  co-resident 4096 waves -> 4x less MLP). Instead: fold the scan into the
//  LAST-FINISHING block of the streaming kernel (done-counter, no spinning).
//
// ws layout: accanyT[BT] bytes ([t][b]), smaskT[BT] ints ([t][b]),
//            counts[32] ints, tabs[32] ints, done[1] int.

#define ALPHA_F 0.001f

typedef int iv4 __attribute__((ext_vector_type(4)));   // native vector for nt-loads

// ---------- Kernel A: stream + tabs; last-finishing block runs the scan ----------
__global__ __launch_bounds__(256) void snn_stream_scan(
    const iv4* __restrict__ frames4, unsigned char* __restrict__ accanyT,
    int* __restrict__ tabs, int* __restrict__ smaskT, int* __restrict__ counts,
    int* __restrict__ done,
    const float* __restrict__ v_th0, const int* __restrict__ neuron_id0,
    const float* __restrict__ mem_map0,
    const float* __restrict__ v_th1, const float* __restrict__ mem_map1,
    int n4, int n_hid, int n_out, int nblocks, int B, int T) {
  int tid = threadIdx.x;
  int wv = tid >> 6, lane = tid & 63;

  __shared__ union {
    int sred[4][16];                  // tab block
    unsigned char accL[128 * 132];    // scan (last block), row stride 132 B
  } u;
  __shared__ int sTab[32];
  __shared__ unsigned long long sHp[2];
  __shared__ int sredc0[4][16], sredc1[4][16];
  __shared__ int sOld;

  if ((int)blockIdx.x < nblocks) {
    // Streaming: wave wv handles bt = blockIdx*4 + wv independently.
    int bt = blockIdx.x * 4 + wv;
    const iv4* fp = frames4 + (size_t)bt * n4;
    int i0 = (lane << 2) & 15;        // loop-invariant: (4*(lane+64k)) & 15
    int x = 0, anyv = 0;
#pragma unroll 5
    for (int idx = lane; idx < n4; idx += 64) {
      iv4 f = __builtin_nontemporal_load(&fp[idx]);
      if (f.x > 0) { x ^= i0;       anyv = 1; }
      if (f.y > 0) { x ^= (i0 + 1); anyv = 1; }
      if (f.z > 0) { x ^= (i0 + 2); anyv = 1; }
      if (f.w > 0) { x ^= (i0 + 3); anyv = 1; }
    }
#pragma unroll
    for (int off = 32; off > 0; off >>= 1) {
      x ^= __shfl_xor(x, off);
      anyv |= __shfl_xor(anyv, off);
    }
    if (lane == 0) {
      int b = bt / T, t = bt % T;                    // frames laid out [B][T]
      accanyT[t * B + b] = (unsigned char)((x & 15) | (anyv << 4));
    }
  } else {
    // Tab block: A1[v] = XOR_j (mem_map0[j,v]>=v_th0[j] ? nid[j] : 0); spike LUT.
    int part[16];
#pragma unroll
    for (int v = 0; v < 16; v++) part[v] = 0;
    for (int j = tid; j < n_hid; j += 256) {
      float vth = v_th0[j];
      int nid = neuron_id0[j];
      const float4* mm = (const float4*)(mem_map0 + (size_t)j * 16);
      float4 m0 = mm[0], m1 = mm[1], m2 = mm[2], m3 = mm[3];
      if (m0.x >= vth) part[0]  ^= nid;
      if (m0.y >= vth) part[1]  ^= nid;
      if (m0.z >= vth) part[2]  ^= nid;
      if (m0.w >= vth) part[3]  ^= nid;
      if (m1.x >= vth) part[4]  ^= nid;
      if (m1.y >= vth) part[5]  ^= nid;
      if (m1.z >= vth) part[6]  ^= nid;
      if (m1.w >= vth) part[7]  ^= nid;
      if (m2.x >= vth) part[8]  ^= nid;
      if (m2.y >= vth) part[9]  ^= nid;
      if (m2.z >= vth) part[10] ^= nid;
      if (m2.w >= vth) part[11] ^= nid;
      if (m3.x >= vth) part[12] ^= nid;
      if (m3.y >= vth) part[13] ^= nid;
      if (m3.z >= vth) part[14] ^= nid;
      if (m3.w >= vth) part[15] ^= nid;
    }
#pragma unroll
    for (int v = 0; v < 16; v++) {
      int xv = part[v];
#pragma unroll
      for (int off = 32; off > 0; off >>= 1) xv ^= __shfl_xor(xv, off);
      if (lane == 0) u.sred[wv][v] = xv;
    }
    __syncthreads();
    if (tid < 16) {
      tabs[tid] = (u.sred[0][tid] ^ u.sred[1][tid] ^ u.sred[2][tid] ^ u.sred[3][tid]) & 15;
      int msk = 0;
      for (int k = 0; k < n_out; k++)
        if (mem_map1[k * 16 + tid] >= v_th1[k]) msk |= (1 << k);
      tabs[16 + tid] = msk;
    }
  }

  // ---- Completion protocol: last-finishing block runs the scan ----
  __syncthreads();
  __threadfence();                       // release: make our stores visible (agent scope)
  if (tid == 0) sOld = atomicAdd(done, 1);
  __syncthreads();
  if (sOld != nblocks) return;           // nblocks+1 blocks total; last sees old==nblocks
  __threadfence();                       // acquire: invalidate caches before reading

  // ---- Scan (runs on exactly one block, all data now visible) ----
  // Coalesced dword copy of accanyT (16 KB, [t][b]) -> padded LDS.
  {
    const int* g4 = (const int*)accanyT;
    int nd = (B * T) >> 2;               // 4096 dwords, 32 per t-row
    for (int i = tid; i < nd; i += 256) {
      int t = i >> 5, k = i & 31;
      *(int*)&u.accL[t * 132 + (k << 2)] = g4[i];
    }
    if (tid < 32) sTab[tid] = tabs[tid];
  }
  __syncthreads();

  // has[t] (OR of any-flags, bit 4 of each byte) -> ballot -> 2 x u64.
  int h = 0;
  if (tid < T) {
    const unsigned int* row = (const unsigned int*)&u.accL[tid * 132];
    unsigned int hh = 0;
#pragma unroll
    for (int k = 0; k < 32; k++) hh |= row[k];
    h = (hh & 0x10101010u) ? 1 : 0;
  }
  unsigned long long bal = __ballot(h);
  if (lane == 0 && wv < 2) sHp[wv] = bal;

  // Register LUTs: A1 as 16x4b in one u64; spike masks as 16x16b in four u64.
  unsigned long long A1p = 0, P0 = 0, P1 = 0, P2 = 0, P3 = 0;
#pragma unroll
  for (int v = 0; v < 16; v++)
    A1p |= (unsigned long long)(sTab[v] & 15) << (v * 4);
#pragma unroll
  for (int v = 0; v < 4; v++) {
    P0 |= (unsigned long long)(sTab[16 + v] & 0xFFFF) << (v * 16);
    P1 |= (unsigned long long)(sTab[20 + v] & 0xFFFF) << (v * 16);
    P2 |= (unsigned long long)(sTab[24 + v] & 0xFFFF) << (v * 16);
    P3 |= (unsigned long long)(sTab[28 + v] & 0xFFFF) << (v * 16);
  }
  __syncthreads();
  unsigned long long Hp0 = sHp[0], Hp1 = sHp[1];

  // Sequential scan: thread tid = batch b; smaskT written directly ([t][b]).
  int myc0[16], myc1[16];
#pragma unroll
  for (int v = 0; v < 16; v++) { myc0[v] = 0; myc1[v] = 0; }

  if (tid < B) {
    int s0 = 0, s1 = 0, tlast = 0;
    unsigned long long c0lo = 0, c0hi = 0, c1lo = 0, c1hi = 0;
    for (int t = 0; t < T; t++) {
      int mask = 0;
      int hasbit = (int)((t < 64 ? (Hp0 >> t) : (Hp1 >> (t - 64))) & 1);
      if (hasbit) {                      // uniform branch
        int a = u.accL[t * 132 + tid] & 15;
        int dt = (t - tlast) & 15;
        s0 ^= dt ^ a;
        unsigned long long inc0 = 1ULL << ((s0 & 7) * 8);
        c0lo += (s0 < 8) ? inc0 : 0;
        c0hi += (s0 < 8) ? 0 : inc0;
        s1 ^= dt ^ (int)((A1p >> (s0 * 4)) & 15);
        unsigned long long inc1 = 1ULL << ((s1 & 7) * 8);
        c1lo += (s1 < 8) ? inc1 : 0;
        c1hi += (s1 < 8) ? 0 : inc1;
        tlast = t;
        unsigned long long q = (s1 & 8) ? ((s1 & 4) ? P3 : P2)
                                        : ((s1 & 4) ? P1 : P0);
        mask = (int)((q >> ((s1 & 3) * 16)) & 0xFFFF);
      }
      smaskT[t * B + tid] = mask;        // coalesced dword stores across b
    }
#pragma unroll
    for (int v = 0; v < 8; v++) {
      myc0[v]     = (int)((c0lo >> (v * 8)) & 0xFF);
      myc0[v + 8] = (int)((c0hi >> (v * 8)) & 0xFF);
      myc1[v]     = (int)((c1lo >> (v * 8)) & 0xFF);
      myc1[v + 8] = (int)((c1hi >> (v * 8)) & 0xFF);
    }
  }

#pragma unroll
  for (int v = 0; v < 16; v++) {
    int a0 = myc0[v], a1 = myc1[v];
#pragma unroll
    for (int off = 32; off > 0; off >>= 1) {
      a0 += __shfl_xor(a0, off);
      a1 += __shfl_xor(a1, off);
    }
    if (lane == 0) { sredc0[wv][v] = a0; sredc1[wv][v] = a1; }
  }
  __syncthreads();
  if (tid < 16) {
    counts[tid]      = sredc0[0][tid] + sredc0[1][tid] + sredc0[2][tid] + sredc0[3][tid];
    counts[16 + tid] = sredc1[0][tid] + sredc1[1][tid] + sredc1[2][tid] + sredc1[3][tid];
  }
}

// ---------- Kernel C: materialize outputs (spikes raster, d0, d1) ----------
__global__ __launch_bounds__(256) void output_kernel(
    const int* __restrict__ smaskT, const int* __restrict__ counts,
    const float* __restrict__ mem_map0, const float* __restrict__ mem_map1,
    float* __restrict__ out, int spikes_n, int d0_n, int d1_n, int n_out, int B, int T) {
  int idx = blockIdx.x * 256 + threadIdx.x;
  if (idx < spikes_n) {
    int k = idx % n_out;
    int bt = idx / n_out;                // bt = b*T + t
    int b = bt / T, t = bt % T;
    out[idx] = (float)((smaskT[t * B + b] >> k) & 1);
  } else if (idx < spikes_n + d0_n) {
    int i2 = idx - spikes_n;
    int v = i2 & 15;
    out[idx] = ALPHA_F * ((float)v - mem_map0[i2]) * (float)counts[v];
  } else if (idx < spikes_n + d0_n + d1_n) {
    int i3 = idx - spikes_n - d0_n;
    int v = i3 & 15;
    out[idx] = ALPHA_F * ((float)v - mem_map1[i3]) * (float)counts[16 + v];
  }
}

extern "C" void kernel_launch(void* const* d_in, const int* in_sizes, int n_in,
                              void* d_out, int out_size, void* d_ws, size_t ws_size,
                              hipStream_t stream) {
  const int*   frames     = (const int*)d_in[0];
  const float* v_th0      = (const float*)d_in[3];
  const int*   neuron_id0 = (const int*)d_in[4];
  const float* mem_map0   = (const float*)d_in[5];
  const float* v_th1      = (const float*)d_in[8];
  const float* mem_map1   = (const float*)d_in[10];

  const int n_in_neurons = in_sizes[1];                 // 2312
  const int n_hid        = in_sizes[2];                 // 2048
  const int n_out        = in_sizes[7];                 // 10
  const int B            = 128;
  const int BT           = in_sizes[0] / n_in_neurons;  // 16384
  const int T            = BT / B;                      // 128

  unsigned char* accanyT = (unsigned char*)d_ws;        // BT bytes, [t][b]
  int* smaskT = (int*)(accanyT + BT);                   // BT ints, [t][b]
  int* counts = smaskT + BT;
  int* tabs   = counts + 32;
  int* done   = tabs + 32;

  hipMemsetAsync(done, 0, sizeof(int), stream);         // ws is poisoned 0xAA

  int nblocks = BT / 4;  // one wave per bt
  snn_stream_scan<<<nblocks + 1, 256, 0, stream>>>(
      (const iv4*)frames, accanyT, tabs, smaskT, counts, done,
      v_th0, neuron_id0, mem_map0, v_th1, mem_map1,
      n_in_neurons / 4, n_hid, n_out, nblocks, B, T);
  int total = BT * n_out + n_hid * 16 + n_out * 16;
  output_kernel<<<(total + 255) / 256, 256, 0, stream>>>(
      smaskT, counts, mem_map0, mem_map1, (float*)d_out,
      BT * n_out, n_hid * 16, n_out * 16, n_out, B, T);
}

// Round 10
// 258.636 us; speedup vs baseline: 3.0389x; 3.0389x over previous
//
#include <hip/hip_runtime.h>

// SNN model, analyzed:
//  - mem_fict (syn_w matmuls, tau decay) is dead state -> skipped entirely.
//  - mem_phys is uniform across neurons -> 4-bit per-batch states s0,s1.
//  - d0[j,v] = ALPHA*(v-mem_map0[j,v]) * C0[v]  (C = visit counts of state v).
//  - Only real work: XOR-reduce of frames (151.5 MB). HBM/L3-bound.
//  NOTES: cooperative fusion regressed 264->492 (co-residency caps MLP);
//  done-counter fold regressed 264->786 (per-block device fence = L2 writeback
//  x4097). This round: 2 kernels, scan recomputed REDUNDANTLY per output block
//  (parallel across CUs, no fences, plain kernel boundary).
//
// ws layout: accanyT[BT] bytes ([t][b]), tabs[32] ints.

#define ALPHA_F 0.001f

typedef int iv4 __attribute__((ext_vector_type(4)));   // native vector for nt-loads

// ---------- Kernel A: one wave per (b,t) XOR-reduce; last block builds LUTs ----------
__global__ __launch_bounds__(256) void frames_reduce_kernel(
    const iv4* __restrict__ frames4, unsigned char* __restrict__ accanyT,
    int* __restrict__ tabs,
    const float* __restrict__ v_th0, const int* __restrict__ neuron_id0,
    const float* __restrict__ mem_map0,
    const float* __restrict__ v_th1, const float* __restrict__ mem_map1,
    int n4, int n_hid, int n_out, int nblocks, int B, int T) {
  int tid = threadIdx.x;
  int wv = tid >> 6, lane = tid & 63;

  if ((int)blockIdx.x < nblocks) {
    // Streaming path: wave wv handles bt = blockIdx*4 + wv independently.
    int bt = blockIdx.x * 4 + wv;
    const iv4* fp = frames4 + (size_t)bt * n4;
    int i0 = (lane << 2) & 15;     // loop-invariant: (4*(lane+64k)) & 15
    int x = 0, anyv = 0;
#pragma unroll 5
    for (int idx = lane; idx < n4; idx += 64) {
      iv4 f = __builtin_nontemporal_load(&fp[idx]);
      if (f.x > 0) { x ^= i0;       anyv = 1; }
      if (f.y > 0) { x ^= (i0 + 1); anyv = 1; }
      if (f.z > 0) { x ^= (i0 + 2); anyv = 1; }
      if (f.w > 0) { x ^= (i0 + 3); anyv = 1; }
    }
#pragma unroll
    for (int off = 32; off > 0; off >>= 1) {
      x ^= __shfl_xor(x, off);
      anyv |= __shfl_xor(anyv, off);
    }
    if (lane == 0) {
      int b = bt / T, t = bt % T;                    // frames laid out [B][T]
      accanyT[t * B + b] = (unsigned char)((x & 15) | (anyv << 4));
    }
    return;
  }

  // Table block: A1[v] = XOR_j (mem_map0[j,v]>=v_th0[j] ? nid[j] : 0); spike LUT.
  int part[16];
#pragma unroll
  for (int v = 0; v < 16; v++) part[v] = 0;
  for (int j = tid; j < n_hid; j += 256) {
    float vth = v_th0[j];
    int nid = neuron_id0[j];
    const float4* mm = (const float4*)(mem_map0 + (size_t)j * 16);
    float4 m0 = mm[0], m1 = mm[1], m2 = mm[2], m3 = mm[3];
    if (m0.x >= vth) part[0]  ^= nid;
    if (m0.y >= vth) part[1]  ^= nid;
    if (m0.z >= vth) part[2]  ^= nid;
    if (m0.w >= vth) part[3]  ^= nid;
    if (m1.x >= vth) part[4]  ^= nid;
    if (m1.y >= vth) part[5]  ^= nid;
    if (m1.z >= vth) part[6]  ^= nid;
    if (m1.w >= vth) part[7]  ^= nid;
    if (m2.x >= vth) part[8]  ^= nid;
    if (m2.y >= vth) part[9]  ^= nid;
    if (m2.z >= vth) part[10] ^= nid;
    if (m2.w >= vth) part[11] ^= nid;
    if (m3.x >= vth) part[12] ^= nid;
    if (m3.y >= vth) part[13] ^= nid;
    if (m3.z >= vth) part[14] ^= nid;
    if (m3.w >= vth) part[15] ^= nid;
  }
  __shared__ int sred[4][16];
#pragma unroll
  for (int v = 0; v < 16; v++) {
    int xv = part[v];
#pragma unroll
    for (int off = 32; off > 0; off >>= 1) xv ^= __shfl_xor(xv, off);
    if (lane == 0) sred[wv][v] = xv;
  }
  __syncthreads();
  if (tid < 16) {
    tabs[tid] = (sred[0][tid] ^ sred[1][tid] ^ sred[2][tid] ^ sred[3][tid]) & 15;
    int msk = 0;
    for (int k = 0; k < n_out; k++)
      if (mem_map1[k * 16 + tid] >= v_th1[k]) msk |= (1 << k);
    tabs[16 + tid] = msk;
  }
}

// ---------- Kernel B: redundant per-block scan + grid-stride output write ----------
__global__ __launch_bounds__(256) void scan_output_kernel(
    const unsigned char* __restrict__ accanyT, const int* __restrict__ tabs,
    const float* __restrict__ mem_map0, const float* __restrict__ mem_map1,
    float* __restrict__ out, int B, int T, int n_hid, int n_out) {
  int tid = threadIdx.x;
  int wv = tid >> 6, lane = tid & 63;

  __shared__ unsigned char accL[128 * 132];   // [t][b], row stride 132 B
  __shared__ unsigned short smL[128 * 132];   // [t][b] spike masks
  __shared__ int sTab[32];
  __shared__ unsigned long long sHp[2];
  __shared__ int sredc0[4][16], sredc1[4][16];
  __shared__ int sCnt[32];

  // Load accanyT (16 KB, L2-broadcast across blocks) -> padded LDS.
  const int* g4 = (const int*)accanyT;
  int nd = (B * T) >> 2;                       // 4096 dwords, 32 per t-row
  for (int i = tid; i < nd; i += 256) {
    int t = i >> 5, k = i & 31;
    *(int*)&accL[t * 132 + (k << 2)] = g4[i];
  }
  if (tid < 32) sTab[tid] = tabs[tid];
  __syncthreads();

  // has[t] (OR of any-flags, bit 4 of each byte) -> ballot -> 2 x u64.
  int h = 0;
  if (tid < T) {
    const unsigned int* row = (const unsigned int*)&accL[tid * 132];
    unsigned int hh = 0;
#pragma unroll
    for (int k = 0; k < 32; k++) hh |= row[k];
    h = (hh & 0x10101010u) ? 1 : 0;
  }
  unsigned long long bal = __ballot(h);
  if (lane == 0 && wv < 2) sHp[wv] = bal;

  // Register LUTs: A1 as 16x4b in one u64; spike masks as 16x16b in four u64.
  unsigned long long A1p = 0, P0 = 0, P1 = 0, P2 = 0, P3 = 0;
#pragma unroll
  for (int v = 0; v < 16; v++)
    A1p |= (unsigned long long)(sTab[v] & 15) << (v * 4);
#pragma unroll
  for (int v = 0; v < 4; v++) {
    P0 |= (unsigned long long)(sTab[16 + v] & 0xFFFF) << (v * 16);
    P1 |= (unsigned long long)(sTab[20 + v] & 0xFFFF) << (v * 16);
    P2 |= (unsigned long long)(sTab[24 + v] & 0xFFFF) << (v * 16);
    P3 |= (unsigned long long)(sTab[28 + v] & 0xFFFF) << (v * 16);
  }
  __syncthreads();
  unsigned long long Hp0 = sHp[0], Hp1 = sHp[1];

  // Sequential scan: thread tid = batch b (redundant per block, parallel across CUs).
  int myc0[16], myc1[16];
#pragma unroll
  for (int v = 0; v < 16; v++) { myc0[v] = 0; myc1[v] = 0; }

  if (tid < B) {
    int s0 = 0, s1 = 0, tlast = 0;
    unsigned long long c0lo = 0, c0hi = 0, c1lo = 0, c1hi = 0;
    for (int t = 0; t < T; t++) {
      int mask = 0;
      int hasbit = (int)((t < 64 ? (Hp0 >> t) : (Hp1 >> (t - 64))) & 1);
      if (hasbit) {                        // uniform branch
        int a = accL[t * 132 + tid] & 15;
        int dt = (t - tlast) & 15;
        s0 ^= dt ^ a;
        unsigned long long inc0 = 1ULL << ((s0 & 7) * 8);
        c0lo += (s0 < 8) ? inc0 : 0;
        c0hi += (s0 < 8) ? 0 : inc0;
        s1 ^= dt ^ (int)((A1p >> (s0 * 4)) & 15);
        unsigned long long inc1 = 1ULL << ((s1 & 7) * 8);
        c1lo += (s1 < 8) ? inc1 : 0;
        c1hi += (s1 < 8) ? 0 : inc1;
        tlast = t;
        unsigned long long q = (s1 & 8) ? ((s1 & 4) ? P3 : P2)
                                        : ((s1 & 4) ? P1 : P0);
        mask = (int)((q >> ((s1 & 3) * 16)) & 0xFFFF);
      }
      smL[t * 132 + tid] = (unsigned short)mask;
    }
#pragma unroll
    for (int v = 0; v < 8; v++) {
      myc0[v]     = (int)((c0lo >> (v * 8)) & 0xFF);
      myc0[v + 8] = (int)((c0hi >> (v * 8)) & 0xFF);
      myc1[v]     = (int)((c1lo >> (v * 8)) & 0xFF);
      myc1[v + 8] = (int)((c1hi >> (v * 8)) & 0xFF);
    }
  }

  // Reduce counts across the block (threads >= B contribute zeros).
#pragma unroll
  for (int v = 0; v < 16; v++) {
    int a0 = myc0[v], a1 = myc1[v];
#pragma unroll
    for (int off = 32; off > 0; off >>= 1) {
      a0 += __shfl_xor(a0, off);
      a1 += __shfl_xor(a1, off);
    }
    if (lane == 0) { sredc0[wv][v] = a0; sredc1[wv][v] = a1; }
  }
  __syncthreads();
  if (tid < 16) {
    sCnt[tid]      = sredc0[0][tid] + sredc0[1][tid] + sredc0[2][tid] + sredc0[3][tid];
    sCnt[16 + tid] = sredc1[0][tid] + sredc1[1][tid] + sredc1[2][tid] + sredc1[3][tid];
  }
  __syncthreads();

  // Grid-stride output write (spikes raster [b][t][k], then d0, then d1).
  int spikes_n = B * T * n_out;
  int d0_n = n_hid * 16, d1_n = n_out * 16;
  int total = spikes_n + d0_n + d1_n;
  for (int idx = blockIdx.x * 256 + tid; idx < total; idx += (int)gridDim.x * 256) {
    if (idx < spikes_n) {
      int k = idx % n_out;
      int bt = idx / n_out;                // bt = b*T + t
      int b = bt >> 7, t = bt & 127;
      out[idx] = (float)((smL[t * 132 + b] >> k) & 1);
    } else if (idx < spikes_n + d0_n) {
      int i2 = idx - spikes_n;
      int v = i2 & 15;
      out[idx] = ALPHA_F * ((float)v - mem_map0[i2]) * (float)sCnt[v];
    } else {
      int i3 = idx - spikes_n - d0_n;
      int v = i3 & 15;
      out[idx] = ALPHA_F * ((float)v - mem_map1[i3]) * (float)sCnt[16 + v];
    }
  }
}

extern "C" void kernel_launch(void* const* d_in, const int* in_sizes, int n_in,
                              void* d_out, int out_size, void* d_ws, size_t ws_size,
                              hipStream_t stream) {
  const int*   frames     = (const int*)d_in[0];
  const float* v_th0      = (const float*)d_in[3];
  const int*   neuron_id0 = (const int*)d_in[4];
  const float* mem_map0   = (const float*)d_in[5];
  const float* v_th1      = (const float*)d_in[8];
  const float* mem_map1   = (const float*)d_in[10];

  const int n_in_neurons = in_sizes[1];                 // 2312
  const int n_hid        = in_sizes[2];                 // 2048
  const int n_out        = in_sizes[7];                 // 10
  const int B            = 128;
  const int BT           = in_sizes[0] / n_in_neurons;  // 16384
  const int T            = BT / B;                      // 128

  unsigned char* accanyT = (unsigned char*)d_ws;        // BT bytes, [t][b]
  int* tabs   = (int*)(accanyT + BT);

  int nblocks = BT / 4;  // one wave per bt
  frames_reduce_kernel<<<nblocks + 1, 256, 0, stream>>>(
      (const iv4*)frames, accanyT, tabs, v_th0, neuron_id0, mem_map0,
      v_th1, mem_map1, n_in_neurons / 4, n_hid, n_out, nblocks, B, T);
  scan_output_kernel<<<192, 256, 0, stream>>>(
      accanyT, tabs, mem_map0, mem_map1, (float*)d_out, B, T, n_hid, n_out);
}